// Round 9
// baseline (244.568 us; speedup 1.0000x reference)
//
#include <hip/hip_runtime.h>
#include <math.h>

#define KCOMP 32
#define DDIM 64
#define LOG_2PI 1.8378770664093453f

// W~ fragment-major layout: frag index f = (comp*2 + r)*5 + s, each frag is
// 1024 B = 64 lanes x 16 B (one half8 per lane). Per comp: 10 frags = 10240 B.
#define WFRAG_HALF8S 64
#define WCOMP_BYTES 10240

typedef _Float16 half8 __attribute__((ext_vector_type(8)));
typedef float floatx16 __attribute__((ext_vector_type(16)));

__device__ inline float rdlane(float v, int l) {
    return __uint_as_float(__builtin_amdgcn_readlane(__float_as_uint(v), l));
}

// ---------------------------------------------------------------------------
// Prep: register-resident Cholesky + triangular inverse, one wave/component.
// Broadcasts via v_readlane BATCHED 8-at-a-time: the v_readlane(SGPR write)
// -> VALU(SGPR read) hazard (~4 wait states) is paid once per batch instead
// of once per term. Per-lane diagonal capture + one logf/lane at the end
// replaces 64 inline uniform logf's. grid = KCOMP blocks x 64 threads.
// ---------------------------------------------------------------------------
__global__ __launch_bounds__(64, 1) void gmm_prep(const float* __restrict__ loc,
                                                  const float* __restrict__ cov,
                                                  const float* __restrict__ pi,
                                                  _Float16* __restrict__ wt,
                                                  float* __restrict__ cstout)
{
    const int k = blockIdx.x;
    const int t = threadIdx.x;

    __shared__ float M[DDIM][DDIM + 1];
    __shared__ float mu_s[DDIM];

    float Srow[DDIM];   // Sigma row t
    float Lrow[DDIM];   // L row t
    float Mcol[DDIM];   // M column t

    {
        const float4* Sg = (const float4*)(cov + (size_t)k * DDIM * DDIM + (size_t)t * DDIM);
        #pragma unroll
        for (int q = 0; q < DDIM / 4; ++q) {
            float4 v = Sg[q];
            Srow[q * 4 + 0] = v.x; Srow[q * 4 + 1] = v.y;
            Srow[q * 4 + 2] = v.z; Srow[q * 4 + 3] = v.w;
        }
    }
    mu_s[t] = loc[k * DDIM + t];

    // ---- left-looking Cholesky, rows in registers, batched broadcasts ----
    float mydiag = 1.f;     // lane t ends up holding d_t (pre-sqrt diagonal)
    #pragma unroll
    for (int j = 0; j < DDIM; ++j) {
        float a[8] = {0.f, 0.f, 0.f, 0.f, 0.f, 0.f, 0.f, 0.f};
        #pragma unroll
        for (int p8 = 0; p8 < j; p8 += 8) {
            float b[8];
            #pragma unroll
            for (int e = 0; e < 8; ++e)
                if (p8 + e < j) b[e] = rdlane(Lrow[p8 + e], j);   // L[j][c]
            #pragma unroll
            for (int e = 0; e < 8; ++e)
                if (p8 + e < j) a[e] += Lrow[p8 + e] * b[e];
        }
        float dot = ((a[0] + a[1]) + (a[2] + a[3])) + ((a[4] + a[5]) + (a[6] + a[7]));
        float v = Srow[j] - dot;
        float dj = rdlane(v, j);                 // diagonal d_j (pre-sqrt)
        float r = rsqrtf(dj);
        r = r * (1.5f - 0.5f * dj * r * r);      // one Newton step
        Lrow[j] = (t >= j) ? v * r : 0.f;
        if (t == j) mydiag = dj;                 // capture, log later
    }

    // half-logdet: one logf per lane, then wave-sum (uniform result)
    float hld;
    {
        float lg = 0.25f * logf(mydiag);         // 0.5 * log(sqrt(d_t)) per lane... 
        // careful: hld = sum_j log(L[j][j]) = sum_j 0.5*log(d_j)
        lg = 0.5f * logf(mydiag);
        #pragma unroll
        for (int w = 1; w < 64; w <<= 1) lg += __shfl_xor(lg, w);
        hld = lg;
    }

    // ---- M = L^{-1}: lane t builds column t, batched broadcasts ----
    #pragma unroll
    for (int i = 0; i < DDIM; ++i) {
        float a[8] = {0.f, 0.f, 0.f, 0.f, 0.f, 0.f, 0.f, 0.f};
        #pragma unroll
        for (int p8 = 0; p8 < i; p8 += 8) {
            float b[8];
            #pragma unroll
            for (int e = 0; e < 8; ++e)
                if (p8 + e < i) b[e] = rdlane(Lrow[p8 + e], i);   // L[i][c]
            #pragma unroll
            for (int e = 0; e < 8; ++e)
                if (p8 + e < i) a[e] += b[e] * Mcol[p8 + e];
        }
        float s = ((a[0] + a[1]) + (a[2] + a[3])) + ((a[4] + a[5]) + (a[6] + a[7]));
        float dinv = 1.0f / rdlane(Lrow[i], i);  // uniform
        Mcol[i] = (t < i) ? (-s * dinv) : ((t == i) ? dinv : 0.f);
    }

    // flush M columns -> LDS rows (one time)
    #pragma unroll
    for (int i = 0; i < DDIM; ++i) M[i][t] = Mcol[i];
    __syncthreads();

    // ---- b_t = sum_j M[t][j] * mu[j] (upper of M is zero) ----
    float bt = 0.f;
    #pragma unroll 4
    for (int j = 0; j < DDIM; ++j) bt += M[t][j] * mu_s[j];

    // ---- emit fragment-major f16 W~: thread t = z-row t ----
    // A-frag for mfma_32x32x16_f16: lane l holds A[l&31][(l>>5)*8 + e].
    // Row t, feature chunk c (8 halves) -> frag s = c>>1, frag-lane
    // fl = (t&31) + 32*(c&1), tile r = t>>5.
    {
        const int r = t >> 5, lrow = t & 31;
        half8* wp = (half8*)wt;
        const size_t fbase = ((size_t)k * 2 + r) * 5;   // frag index base
        #pragma unroll
        for (int c = 0; c < 8; ++c) {          // data chunks: M row
            half8 v;
            #pragma unroll
            for (int e = 0; e < 8; ++e) v[e] = (_Float16)M[t][c * 8 + e];
            int fl = lrow + 32 * (c & 1);
            wp[(fbase + (c >> 1)) * WFRAG_HALF8S + fl] = v;
        }
        {   // chunk 8 (s=4, fl=lrow): -b split hi/lo (pairs with x~=1,1)
            float nb = -bt;
            _Float16 h0 = (_Float16)nb;
            _Float16 h1 = (_Float16)(nb - (float)h0);
            half8 v;
            #pragma unroll
            for (int e = 0; e < 8; ++e) v[e] = (_Float16)0.f;
            v[0] = h0; v[1] = h1;
            wp[(fbase + 4) * WFRAG_HALF8S + lrow] = v;
        }
        {   // chunk 9 (s=4, fl=lrow+32): zeros
            half8 v;
            #pragma unroll
            for (int e = 0; e < 8; ++e) v[e] = (_Float16)0.f;
            wp[(fbase + 4) * WFRAG_HALF8S + lrow + 32] = v;
        }
    }

    if (t == 0) {
        float mxp = pi[0];
        for (int i = 1; i < KCOMP; ++i) mxp = fmaxf(mxp, pi[i]);
        float s = 0.f;
        for (int i = 0; i < KCOMP; ++i) s += __expf(pi[i] - mxp);
        float lse = mxp + logf(s);
        cstout[k] = (pi[k] - lse) - hld - 0.5f * (float)DDIM * LOG_2PI;
    }
}

// ---------------------------------------------------------------------------
// Main: UNCHANGED from round 8 (isolate the prep delta). No LDS staging,
// no hot-loop barriers. Block = 4 waves = 4 component slices (8 comps each)
// over the SAME 128 points; W~ fragments stream L2 -> regs double-buffered.
// ---------------------------------------------------------------------------
__global__ __launch_bounds__(256, 1) void gmm_main(const float* __restrict__ X,
                                                   const _Float16* __restrict__ wt,
                                                   const float* __restrict__ cst,
                                                   float* __restrict__ out)
{
    __shared__ float2 part[4][128];       // [slice][point] partial (mx, sm)

    const int tid  = threadIdx.x;
    const int wave = tid >> 6;            // = component slice
    const int lane = tid & 63;
    const int col  = lane & 31;
    const int h    = lane >> 5;
    const int ptbase = blockIdx.x * 128;

    // ---- build B fragments (x~) for 4 point-groups of 32 ----
    half8 bf[4][5];
    #pragma unroll
    for (int g = 0; g < 4; ++g) {
        const float* xr = X + (size_t)(ptbase + g * 32 + col) * DDIM;
        #pragma unroll
        for (int s = 0; s < 4; ++s) {
            int c = s * 2 + h;
            float4 lo = *(const float4*)(xr + c * 8);
            float4 hi = *(const float4*)(xr + c * 8 + 4);
            half8 v;
            v[0] = (_Float16)lo.x; v[1] = (_Float16)lo.y;
            v[2] = (_Float16)lo.z; v[3] = (_Float16)lo.w;
            v[4] = (_Float16)hi.x; v[5] = (_Float16)hi.y;
            v[6] = (_Float16)hi.z; v[7] = (_Float16)hi.w;
            bf[g][s] = v;
        }
        half8 v;
        #pragma unroll
        for (int e = 0; e < 8; ++e) v[e] = (_Float16)0.f;
        if (h == 0) { v[0] = (_Float16)1.f; v[1] = (_Float16)1.f; }
        bf[g][4] = v;   // augmented slice: pairs with (-b_hi, -b_lo)
    }

    const half8* wp = (const half8*)wt;
    const int comp0 = wave * 8;

    float mx[4], sm[4];
    #pragma unroll
    for (int g = 0; g < 4; ++g) { mx[g] = -INFINITY; sm[g] = 0.f; }

    half8 wfA[5], wfB[5];
    // preload tile-0 frags of first comp
    #pragma unroll
    for (int s = 0; s < 5; ++s)
        wfA[s] = wp[((size_t)comp0 * 2 + 0) * 5 * WFRAG_HALF8S + s * WFRAG_HALF8S + lane];

    #pragma unroll 1
    for (int q = 0; q < 8; ++q) {
        const int c = comp0 + q;

        // issue tile-1 frag loads (overlap with tile-0 MFMA below)
        #pragma unroll
        for (int s = 0; s < 5; ++s)
            wfB[s] = wp[((size_t)c * 2 + 1) * 5 * WFRAG_HALF8S + s * WFRAG_HALF8S + lane];

        float sP[4];

        {   // tile 0: z-rows 0..31
            floatx16 a0 = {0.f}, a1 = {0.f}, a2 = {0.f}, a3 = {0.f};
            #pragma unroll
            for (int s = 0; s < 5; ++s) {
                a0 = __builtin_amdgcn_mfma_f32_32x32x16_f16(wfA[s], bf[0][s], a0, 0, 0, 0);
                a1 = __builtin_amdgcn_mfma_f32_32x32x16_f16(wfA[s], bf[1][s], a1, 0, 0, 0);
                a2 = __builtin_amdgcn_mfma_f32_32x32x16_f16(wfA[s], bf[2][s], a2, 0, 0, 0);
                a3 = __builtin_amdgcn_mfma_f32_32x32x16_f16(wfA[s], bf[3][s], a3, 0, 0, 0);
            }
            float p0 = 0.f, p1 = 0.f, p2 = 0.f, p3 = 0.f;
            #pragma unroll
            for (int r = 0; r < 16; ++r) {
                p0 += a0[r] * a0[r]; p1 += a1[r] * a1[r];
                p2 += a2[r] * a2[r]; p3 += a3[r] * a3[r];
            }
            sP[0] = p0; sP[1] = p1; sP[2] = p2; sP[3] = p3;
        }

        // issue next comp's tile-0 loads (overlap with tile-1 MFMA below)
        if (q < 7) {
            #pragma unroll
            for (int s = 0; s < 5; ++s)
                wfA[s] = wp[((size_t)(c + 1) * 2 + 0) * 5 * WFRAG_HALF8S + s * WFRAG_HALF8S + lane];
        }

        {   // tile 1: z-rows 32..63
            floatx16 a0 = {0.f}, a1 = {0.f}, a2 = {0.f}, a3 = {0.f};
            #pragma unroll
            for (int s = 0; s < 5; ++s) {
                a0 = __builtin_amdgcn_mfma_f32_32x32x16_f16(wfB[s], bf[0][s], a0, 0, 0, 0);
                a1 = __builtin_amdgcn_mfma_f32_32x32x16_f16(wfB[s], bf[1][s], a1, 0, 0, 0);
                a2 = __builtin_amdgcn_mfma_f32_32x32x16_f16(wfB[s], bf[2][s], a2, 0, 0, 0);
                a3 = __builtin_amdgcn_mfma_f32_32x32x16_f16(wfB[s], bf[3][s], a3, 0, 0, 0);
            }
            float p0 = 0.f, p1 = 0.f, p2 = 0.f, p3 = 0.f;
            #pragma unroll
            for (int r = 0; r < 16; ++r) {
                p0 += a0[r] * a0[r]; p1 += a1[r] * a1[r];
                p2 += a2[r] * a2[r]; p3 += a3[r] * a3[r];
            }
            sP[0] += p0; sP[1] += p1; sP[2] += p2; sP[3] += p3;
        }

        const float ck = cst[c];
        #pragma unroll
        for (int g = 0; g < 4; ++g) {
            float sfull = sP[g] + __shfl_xor(sP[g], 32);
            float lp = ck - 0.5f * sfull;
            float nm = fmaxf(mx[g], lp);
            sm[g] = sm[g] * __expf(mx[g] - nm) + __expf(lp - nm);
            mx[g] = nm;
        }
    }

    // ---- merge the 4 slices in-block ----
    if (h == 0) {
        #pragma unroll
        for (int g = 0; g < 4; ++g)
            part[wave][g * 32 + col] = make_float2(mx[g], sm[g]);
    }
    __syncthreads();

    if (tid < 128) {
        float2 p0 = part[0][tid], p1 = part[1][tid];
        float2 p2 = part[2][tid], p3 = part[3][tid];
        float m = fmaxf(fmaxf(p0.x, p1.x), fmaxf(p2.x, p3.x));
        float s = p0.y * __expf(p0.x - m) + p1.y * __expf(p1.x - m)
                + p2.y * __expf(p2.x - m) + p3.y * __expf(p3.x - m);
        out[ptbase + tid] = m + logf(s);
    }
}

// ---------------------------------------------------------------------------
extern "C" void kernel_launch(void* const* d_in, const int* in_sizes, int n_in,
                              void* d_out, int out_size, void* d_ws, size_t ws_size,
                              hipStream_t stream) {
    const float* X   = (const float*)d_in[0];
    const float* loc = (const float*)d_in[1];
    const float* cov = (const float*)d_in[2];
    const float* pi  = (const float*)d_in[3];
    float* out = (float*)d_out;

    char* ws = (char*)d_ws;
    _Float16* wt = (_Float16*)ws;                              // 320 KB
    float* cstp  = (float*)(ws + (size_t)KCOMP * WCOMP_BYTES); // 128 B

    const int n = in_sizes[0] / DDIM;   // 65536

    gmm_prep<<<KCOMP, 64, 0, stream>>>(loc, cov, pi, wt, cstp);
    gmm_main<<<n / 128, 256, 0, stream>>>(X, wt, cstp, out);
}

// Round 10
// 56.257 us; speedup vs baseline: 4.3473x; 4.3473x over previous
//
#include <hip/hip_runtime.h>
#include <math.h>

#define KCOMP 32
#define DDIM 64
#define LOG_2PI 1.8378770664093453f

// W~ fragment-major layout: frag index f = (comp*2 + r)*5 + s, each frag is
// 1024 B = 64 lanes x 16 B (one half8 per lane). Per comp: 10 frags = 10240 B.
#define WFRAG_HALF8S 64
#define WCOMP_BYTES 10240

typedef _Float16 half8 __attribute__((ext_vector_type(8)));
typedef float floatx16 __attribute__((ext_vector_type(16)));

__device__ inline float rdlane(float v, int l) {
    return __uint_as_float(__builtin_amdgcn_readlane(__float_as_uint(v), l));
}

// ---------------------------------------------------------------------------
// Fully-static triangular steps via recursive template instantiation.
// All array indices are compile-time constants -> arrays stay in VGPRs
// (rule: runtime-indexed register arrays spill to scratch).
// Batches of 8 readlanes then 8 FMAs: SGPR-write hazard paid once per batch.
// Padded (unconditional) batches are safe because Lrow/Mcol are zero-init.
// ---------------------------------------------------------------------------
template <int J>
__device__ __forceinline__ void chol_step(float (&Srow)[DDIM], float (&Lrow)[DDIM],
                                          float& mydiag, const int t) {
    constexpr int NPAD = ((J + 7) / 8) * 8;
    float a[8] = {0.f, 0.f, 0.f, 0.f, 0.f, 0.f, 0.f, 0.f};
    #pragma unroll
    for (int p8 = 0; p8 < NPAD; p8 += 8) {
        float b[8];
        #pragma unroll
        for (int e = 0; e < 8; ++e) b[e] = rdlane(Lrow[p8 + e], J);  // L[J][c]
        #pragma unroll
        for (int e = 0; e < 8; ++e) a[e] += Lrow[p8 + e] * b[e];
    }
    float dot = ((a[0] + a[1]) + (a[2] + a[3])) + ((a[4] + a[5]) + (a[6] + a[7]));
    float v  = Srow[J] - dot;
    float dj = rdlane(v, J);                 // diagonal d_J (pre-sqrt), uniform
    float r  = rsqrtf(dj);
    r = r * (1.5f - 0.5f * dj * r * r);      // one Newton step
    Lrow[J] = (t >= J) ? v * r : 0.f;
    if (t == J) mydiag = dj;
}

template <int J>
__device__ __forceinline__ void chol_run(float (&Srow)[DDIM], float (&Lrow)[DDIM],
                                         float& mydiag, const int t) {
    chol_step<J>(Srow, Lrow, mydiag, t);
    if constexpr (J + 1 < DDIM) chol_run<J + 1>(Srow, Lrow, mydiag, t);
}

template <int I>
__device__ __forceinline__ void inv_step(float (&Lrow)[DDIM], float (&Mcol)[DDIM],
                                         const int t) {
    constexpr int NPAD = ((I + 7) / 8) * 8;  // may include c in [I, NPAD): L[I][c>I]=0, Mcol[I]=0-init
    float a[8] = {0.f, 0.f, 0.f, 0.f, 0.f, 0.f, 0.f, 0.f};
    #pragma unroll
    for (int p8 = 0; p8 < NPAD; p8 += 8) {
        float b[8];
        #pragma unroll
        for (int e = 0; e < 8; ++e) b[e] = rdlane(Lrow[p8 + e], I);  // L[I][c]
        #pragma unroll
        for (int e = 0; e < 8; ++e) a[e] += b[e] * Mcol[p8 + e];
    }
    float s = ((a[0] + a[1]) + (a[2] + a[3])) + ((a[4] + a[5]) + (a[6] + a[7]));
    float dinv = 1.0f / rdlane(Lrow[I], I);  // uniform
    Mcol[I] = (t < I) ? (-s * dinv) : ((t == I) ? dinv : 0.f);
}

template <int I>
__device__ __forceinline__ void inv_run(float (&Lrow)[DDIM], float (&Mcol)[DDIM],
                                        const int t) {
    inv_step<I>(Lrow, Mcol, t);
    if constexpr (I + 1 < DDIM) inv_run<I + 1>(Lrow, Mcol, t);
}

// ---------------------------------------------------------------------------
// Prep: register-resident Cholesky + triangular inverse, one wave/component.
// grid = KCOMP blocks x 64 threads.
// ---------------------------------------------------------------------------
__global__ __launch_bounds__(64, 1) void gmm_prep(const float* __restrict__ loc,
                                                  const float* __restrict__ cov,
                                                  const float* __restrict__ pi,
                                                  _Float16* __restrict__ wt,
                                                  float* __restrict__ cstout)
{
    const int k = blockIdx.x;
    const int t = threadIdx.x;

    __shared__ float M[DDIM][DDIM + 1];
    __shared__ float mu_s[DDIM];

    float Srow[DDIM];   // Sigma row t
    float Lrow[DDIM];   // L row t      (zero-init: padding safety)
    float Mcol[DDIM];   // M column t   (zero-init: padding safety)

    {
        const float4* Sg = (const float4*)(cov + (size_t)k * DDIM * DDIM + (size_t)t * DDIM);
        #pragma unroll
        for (int q = 0; q < DDIM / 4; ++q) {
            float4 v = Sg[q];
            Srow[q * 4 + 0] = v.x; Srow[q * 4 + 1] = v.y;
            Srow[q * 4 + 2] = v.z; Srow[q * 4 + 3] = v.w;
        }
    }
    #pragma unroll
    for (int i = 0; i < DDIM; ++i) { Lrow[i] = 0.f; Mcol[i] = 0.f; }
    mu_s[t] = loc[k * DDIM + t];

    // ---- left-looking Cholesky, rows in registers ----
    float mydiag = 1.f;                      // lane t ends holding d_t
    chol_run<0>(Srow, Lrow, mydiag, t);

    // half-logdet = sum_j 0.5*log(d_j): one logf per lane + wave-sum
    float hld;
    {
        float lg = 0.5f * logf(mydiag);
        #pragma unroll
        for (int w = 1; w < 64; w <<= 1) lg += __shfl_xor(lg, w);
        hld = lg;
    }

    // ---- M = L^{-1}: lane t builds column t ----
    inv_run<0>(Lrow, Mcol, t);

    // flush M columns -> LDS rows (one time)
    #pragma unroll
    for (int i = 0; i < DDIM; ++i) M[i][t] = Mcol[i];
    __syncthreads();

    // ---- b_t = sum_j M[t][j] * mu[j] (upper of M is zero) ----
    float bt = 0.f;
    #pragma unroll 4
    for (int j = 0; j < DDIM; ++j) bt += M[t][j] * mu_s[j];

    // ---- emit fragment-major f16 W~: thread t = z-row t ----
    // A-frag for mfma_32x32x16_f16: lane l holds A[l&31][(l>>5)*8 + e].
    // Row t, feature chunk c (8 halves) -> frag s = c>>1, frag-lane
    // fl = (t&31) + 32*(c&1), tile r = t>>5.
    {
        const int r = t >> 5, lrow = t & 31;
        half8* wp = (half8*)wt;
        const size_t fbase = ((size_t)k * 2 + r) * 5;   // frag index base
        #pragma unroll
        for (int c = 0; c < 8; ++c) {          // data chunks: M row
            half8 v;
            #pragma unroll
            for (int e = 0; e < 8; ++e) v[e] = (_Float16)M[t][c * 8 + e];
            int fl = lrow + 32 * (c & 1);
            wp[(fbase + (c >> 1)) * WFRAG_HALF8S + fl] = v;
        }
        {   // chunk 8 (s=4, fl=lrow): -b split hi/lo (pairs with x~=1,1)
            float nb = -bt;
            _Float16 h0 = (_Float16)nb;
            _Float16 h1 = (_Float16)(nb - (float)h0);
            half8 v;
            #pragma unroll
            for (int e = 0; e < 8; ++e) v[e] = (_Float16)0.f;
            v[0] = h0; v[1] = h1;
            wp[(fbase + 4) * WFRAG_HALF8S + lrow] = v;
        }
        {   // chunk 9 (s=4, fl=lrow+32): zeros
            half8 v;
            #pragma unroll
            for (int e = 0; e < 8; ++e) v[e] = (_Float16)0.f;
            wp[(fbase + 4) * WFRAG_HALF8S + lrow + 32] = v;
        }
    }

    if (t == 0) {
        float mxp = pi[0];
        for (int i = 1; i < KCOMP; ++i) mxp = fmaxf(mxp, pi[i]);
        float s = 0.f;
        for (int i = 0; i < KCOMP; ++i) s += __expf(pi[i] - mxp);
        float lse = mxp + logf(s);
        cstout[k] = (pi[k] - lse) - hld - 0.5f * (float)DDIM * LOG_2PI;
    }
}

// ---------------------------------------------------------------------------
// Main: UNCHANGED from round 8. No LDS staging, no hot-loop barriers.
// Block = 4 waves = 4 component slices (8 comps each) over the SAME 128
// points; W~ fragments stream L2 -> regs double-buffered.
// ---------------------------------------------------------------------------
__global__ __launch_bounds__(256, 1) void gmm_main(const float* __restrict__ X,
                                                   const _Float16* __restrict__ wt,
                                                   const float* __restrict__ cst,
                                                   float* __restrict__ out)
{
    __shared__ float2 part[4][128];       // [slice][point] partial (mx, sm)

    const int tid  = threadIdx.x;
    const int wave = tid >> 6;            // = component slice
    const int lane = tid & 63;
    const int col  = lane & 31;
    const int h    = lane >> 5;
    const int ptbase = blockIdx.x * 128;

    // ---- build B fragments (x~) for 4 point-groups of 32 ----
    half8 bf[4][5];
    #pragma unroll
    for (int g = 0; g < 4; ++g) {
        const float* xr = X + (size_t)(ptbase + g * 32 + col) * DDIM;
        #pragma unroll
        for (int s = 0; s < 4; ++s) {
            int c = s * 2 + h;
            float4 lo = *(const float4*)(xr + c * 8);
            float4 hi = *(const float4*)(xr + c * 8 + 4);
            half8 v;
            v[0] = (_Float16)lo.x; v[1] = (_Float16)lo.y;
            v[2] = (_Float16)lo.z; v[3] = (_Float16)lo.w;
            v[4] = (_Float16)hi.x; v[5] = (_Float16)hi.y;
            v[6] = (_Float16)hi.z; v[7] = (_Float16)hi.w;
            bf[g][s] = v;
        }
        half8 v;
        #pragma unroll
        for (int e = 0; e < 8; ++e) v[e] = (_Float16)0.f;
        if (h == 0) { v[0] = (_Float16)1.f; v[1] = (_Float16)1.f; }
        bf[g][4] = v;   // augmented slice: pairs with (-b_hi, -b_lo)
    }

    const half8* wp = (const half8*)wt;
    const int comp0 = wave * 8;

    float mx[4], sm[4];
    #pragma unroll
    for (int g = 0; g < 4; ++g) { mx[g] = -INFINITY; sm[g] = 0.f; }

    half8 wfA[5], wfB[5];
    // preload tile-0 frags of first comp
    #pragma unroll
    for (int s = 0; s < 5; ++s)
        wfA[s] = wp[((size_t)comp0 * 2 + 0) * 5 * WFRAG_HALF8S + s * WFRAG_HALF8S + lane];

    #pragma unroll 1
    for (int q = 0; q < 8; ++q) {
        const int c = comp0 + q;

        // issue tile-1 frag loads (overlap with tile-0 MFMA below)
        #pragma unroll
        for (int s = 0; s < 5; ++s)
            wfB[s] = wp[((size_t)c * 2 + 1) * 5 * WFRAG_HALF8S + s * WFRAG_HALF8S + lane];

        float sP[4];

        {   // tile 0: z-rows 0..31
            floatx16 a0 = {0.f}, a1 = {0.f}, a2 = {0.f}, a3 = {0.f};
            #pragma unroll
            for (int s = 0; s < 5; ++s) {
                a0 = __builtin_amdgcn_mfma_f32_32x32x16_f16(wfA[s], bf[0][s], a0, 0, 0, 0);
                a1 = __builtin_amdgcn_mfma_f32_32x32x16_f16(wfA[s], bf[1][s], a1, 0, 0, 0);
                a2 = __builtin_amdgcn_mfma_f32_32x32x16_f16(wfA[s], bf[2][s], a2, 0, 0, 0);
                a3 = __builtin_amdgcn_mfma_f32_32x32x16_f16(wfA[s], bf[3][s], a3, 0, 0, 0);
            }
            float p0 = 0.f, p1 = 0.f, p2 = 0.f, p3 = 0.f;
            #pragma unroll
            for (int r = 0; r < 16; ++r) {
                p0 += a0[r] * a0[r]; p1 += a1[r] * a1[r];
                p2 += a2[r] * a2[r]; p3 += a3[r] * a3[r];
            }
            sP[0] = p0; sP[1] = p1; sP[2] = p2; sP[3] = p3;
        }

        // issue next comp's tile-0 loads (overlap with tile-1 MFMA below)
        if (q < 7) {
            #pragma unroll
            for (int s = 0; s < 5; ++s)
                wfA[s] = wp[((size_t)(c + 1) * 2 + 0) * 5 * WFRAG_HALF8S + s * WFRAG_HALF8S + lane];
        }

        {   // tile 1: z-rows 32..63
            floatx16 a0 = {0.f}, a1 = {0.f}, a2 = {0.f}, a3 = {0.f};
            #pragma unroll
            for (int s = 0; s < 5; ++s) {
                a0 = __builtin_amdgcn_mfma_f32_32x32x16_f16(wfB[s], bf[0][s], a0, 0, 0, 0);
                a1 = __builtin_amdgcn_mfma_f32_32x32x16_f16(wfB[s], bf[1][s], a1, 0, 0, 0);
                a2 = __builtin_amdgcn_mfma_f32_32x32x16_f16(wfB[s], bf[2][s], a2, 0, 0, 0);
                a3 = __builtin_amdgcn_mfma_f32_32x32x16_f16(wfB[s], bf[3][s], a3, 0, 0, 0);
            }
            float p0 = 0.f, p1 = 0.f, p2 = 0.f, p3 = 0.f;
            #pragma unroll
            for (int r = 0; r < 16; ++r) {
                p0 += a0[r] * a0[r]; p1 += a1[r] * a1[r];
                p2 += a2[r] * a2[r]; p3 += a3[r] * a3[r];
            }
            sP[0] += p0; sP[1] += p1; sP[2] += p2; sP[3] += p3;
        }

        const float ck = cst[c];
        #pragma unroll
        for (int g = 0; g < 4; ++g) {
            float sfull = sP[g] + __shfl_xor(sP[g], 32);
            float lp = ck - 0.5f * sfull;
            float nm = fmaxf(mx[g], lp);
            sm[g] = sm[g] * __expf(mx[g] - nm) + __expf(lp - nm);
            mx[g] = nm;
        }
    }

    // ---- merge the 4 slices in-block ----
    if (h == 0) {
        #pragma unroll
        for (int g = 0; g < 4; ++g)
            part[wave][g * 32 + col] = make_float2(mx[g], sm[g]);
    }
    __syncthreads();

    if (tid < 128) {
        float2 p0 = part[0][tid], p1 = part[1][tid];
        float2 p2 = part[2][tid], p3 = part[3][tid];
        float m = fmaxf(fmaxf(p0.x, p1.x), fmaxf(p2.x, p3.x));
        float s = p0.y * __expf(p0.x - m) + p1.y * __expf(p1.x - m)
                + p2.y * __expf(p2.x - m) + p3.y * __expf(p3.x - m);
        out[ptbase + tid] = m + logf(s);
    }
}

// ---------------------------------------------------------------------------
extern "C" void kernel_launch(void* const* d_in, const int* in_sizes, int n_in,
                              void* d_out, int out_size, void* d_ws, size_t ws_size,
                              hipStream_t stream) {
    const float* X   = (const float*)d_in[0];
    const float* loc = (const float*)d_in[1];
    const float* cov = (const float*)d_in[2];
    const float* pi  = (const float*)d_in[3];
    float* out = (float*)d_out;

    char* ws = (char*)d_ws;
    _Float16* wt = (_Float16*)ws;                              // 320 KB
    float* cstp  = (float*)(ws + (size_t)KCOMP * WCOMP_BYTES); // 128 B

    const int n = in_sizes[0] / DDIM;   // 65536

    gmm_prep<<<KCOMP, 64, 0, stream>>>(loc, cov, pi, wt, cstp);
    gmm_main<<<n / 128, 256, 0, stream>>>(X, wt, cstp, out);
}

// Round 11
// 51.265 us; speedup vs baseline: 4.7707x; 1.0974x over previous
//
#include <hip/hip_runtime.h>
#include <math.h>

#define KCOMP 32
#define DDIM 64
#define LOG_2PI 1.8378770664093453f

// W~ fragment-major layout: frag index f = (comp*2 + r)*5 + s, each frag is
// 1024 B = 64 lanes x 16 B (one half8 per lane). Per comp: 10 frags = 10240 B.
#define WFRAG_HALF8S 64
#define WCOMP_BYTES 10240

typedef _Float16 half8 __attribute__((ext_vector_type(8)));
typedef float floatx16 __attribute__((ext_vector_type(16)));

__device__ inline float rdlane(float v, int l) {
    return __uint_as_float(__builtin_amdgcn_readlane(__float_as_uint(v), l));
}

// ---------------------------------------------------------------------------
// FUSED Cholesky + triangular-inverse step, fully static (template J).
// Per step J:  b[c] = L[J][c] (one readlane batch, shared by BOTH dots)
//   chol dot: a += Lrow[c] * b[c]      -> column J of L
//   inv  dot: m += b[c] * Mcol[c]      -> row J of M (forward substitution)
// Mcol[J] = t<J ? -m*r : (t==J ? r : 0)  where r = 1/sqrt(d_J) = 1/L[J][J].
// Padding safety: Lrow/Mcol zero-init; at step J, Lrow[c>=J]=0 and the
// inv-sum's c<t terms hit Mcol[c<t]=0.
// ---------------------------------------------------------------------------
template <int J>
__device__ __forceinline__ void fused_step(float (&Srow)[DDIM], float (&Lrow)[DDIM],
                                           float (&Mcol)[DDIM], float& mydiag,
                                           const int t) {
    constexpr int NPAD = ((J + 7) / 8) * 8;
    float a[8] = {0.f, 0.f, 0.f, 0.f, 0.f, 0.f, 0.f, 0.f};
    float m[8] = {0.f, 0.f, 0.f, 0.f, 0.f, 0.f, 0.f, 0.f};
    #pragma unroll
    for (int p8 = 0; p8 < NPAD; p8 += 8) {
        float b[8];
        #pragma unroll
        for (int e = 0; e < 8; ++e) b[e] = rdlane(Lrow[p8 + e], J);  // L[J][c]
        #pragma unroll
        for (int e = 0; e < 8; ++e) {
            a[e] += Lrow[p8 + e] * b[e];
            m[e] += b[e] * Mcol[p8 + e];
        }
    }
    float dot = ((a[0] + a[1]) + (a[2] + a[3])) + ((a[4] + a[5]) + (a[6] + a[7]));
    float ms  = ((m[0] + m[1]) + (m[2] + m[3])) + ((m[4] + m[5]) + (m[6] + m[7]));
    float v  = Srow[J] - dot;
    float dj = rdlane(v, J);                 // diagonal d_J (pre-sqrt), uniform
    float r  = rsqrtf(dj);
    r = r * (1.5f - 0.5f * dj * r * r);      // one Newton step
    Lrow[J] = (t >= J) ? v * r : 0.f;
    Mcol[J] = (t < J) ? (-ms * r) : ((t == J) ? r : 0.f);
    if (t == J) mydiag = dj;
}

template <int J>
__device__ __forceinline__ void fused_run(float (&Srow)[DDIM], float (&Lrow)[DDIM],
                                          float (&Mcol)[DDIM], float& mydiag,
                                          const int t) {
    fused_step<J>(Srow, Lrow, Mcol, mydiag, t);
    if constexpr (J + 1 < DDIM) fused_run<J + 1>(Srow, Lrow, Mcol, mydiag, t);
}

// ---------------------------------------------------------------------------
// Prep: register-resident fused Cholesky+inverse, one wave/component.
// grid = KCOMP blocks x 64 threads.
// ---------------------------------------------------------------------------
__global__ __launch_bounds__(64, 1) void gmm_prep(const float* __restrict__ loc,
                                                  const float* __restrict__ cov,
                                                  const float* __restrict__ pi,
                                                  _Float16* __restrict__ wt,
                                                  float* __restrict__ cstout)
{
    const int k = blockIdx.x;
    const int t = threadIdx.x;

    __shared__ float M[DDIM][DDIM + 1];
    __shared__ float mu_s[DDIM];

    float Srow[DDIM];   // Sigma row t
    float Lrow[DDIM];   // L row t      (zero-init: padding safety)
    float Mcol[DDIM];   // M column t   (zero-init: padding safety)

    {
        const float4* Sg = (const float4*)(cov + (size_t)k * DDIM * DDIM + (size_t)t * DDIM);
        #pragma unroll
        for (int q = 0; q < DDIM / 4; ++q) {
            float4 v = Sg[q];
            Srow[q * 4 + 0] = v.x; Srow[q * 4 + 1] = v.y;
            Srow[q * 4 + 2] = v.z; Srow[q * 4 + 3] = v.w;
        }
    }
    #pragma unroll
    for (int i = 0; i < DDIM; ++i) { Lrow[i] = 0.f; Mcol[i] = 0.f; }
    mu_s[t] = loc[k * DDIM + t];

    // ---- fused left-looking Cholesky + forward-substitution inverse ----
    float mydiag = 1.f;                      // lane t ends holding d_t
    fused_run<0>(Srow, Lrow, Mcol, mydiag, t);

    // half-logdet = sum_j 0.5*log(d_j): one logf per lane + wave-sum
    float hld;
    {
        float lg = 0.5f * logf(mydiag);
        #pragma unroll
        for (int w = 1; w < 64; w <<= 1) lg += __shfl_xor(lg, w);
        hld = lg;
    }

    // flush M columns -> LDS rows (one time)
    #pragma unroll
    for (int i = 0; i < DDIM; ++i) M[i][t] = Mcol[i];
    __syncthreads();

    // ---- b_t = sum_j M[t][j] * mu[j] (upper of M is zero) ----
    float bt = 0.f;
    #pragma unroll 4
    for (int j = 0; j < DDIM; ++j) bt += M[t][j] * mu_s[j];

    // ---- emit fragment-major f16 W~: thread t = z-row t ----
    // A-frag for mfma_32x32x16_f16: lane l holds A[l&31][(l>>5)*8 + e].
    // Row t, feature chunk c (8 halves) -> frag s = c>>1, frag-lane
    // fl = (t&31) + 32*(c&1), tile r = t>>5.
    {
        const int r = t >> 5, lrow = t & 31;
        half8* wp = (half8*)wt;
        const size_t fbase = ((size_t)k * 2 + r) * 5;   // frag index base
        #pragma unroll
        for (int c = 0; c < 8; ++c) {          // data chunks: M row
            half8 v;
            #pragma unroll
            for (int e = 0; e < 8; ++e) v[e] = (_Float16)M[t][c * 8 + e];
            int fl = lrow + 32 * (c & 1);
            wp[(fbase + (c >> 1)) * WFRAG_HALF8S + fl] = v;
        }
        {   // chunk 8 (s=4, fl=lrow): -b split hi/lo (pairs with x~=1,1)
            float nb = -bt;
            _Float16 h0 = (_Float16)nb;
            _Float16 h1 = (_Float16)(nb - (float)h0);
            half8 v;
            #pragma unroll
            for (int e = 0; e < 8; ++e) v[e] = (_Float16)0.f;
            v[0] = h0; v[1] = h1;
            wp[(fbase + 4) * WFRAG_HALF8S + lrow] = v;
        }
        {   // chunk 9 (s=4, fl=lrow+32): zeros
            half8 v;
            #pragma unroll
            for (int e = 0; e < 8; ++e) v[e] = (_Float16)0.f;
            wp[(fbase + 4) * WFRAG_HALF8S + lrow + 32] = v;
        }
    }

    if (t == 0) {
        float mxp = pi[0];
        for (int i = 1; i < KCOMP; ++i) mxp = fmaxf(mxp, pi[i]);
        float s = 0.f;
        for (int i = 0; i < KCOMP; ++i) s += __expf(pi[i] - mxp);
        float lse = mxp + logf(s);
        cstout[k] = (pi[k] - lse) - hld - 0.5f * (float)DDIM * LOG_2PI;
    }
}

// ---------------------------------------------------------------------------
// Main: UNCHANGED from round 8. No LDS staging, no hot-loop barriers.
// Block = 4 waves = 4 component slices (8 comps each) over the SAME 128
// points; W~ fragments stream L2 -> regs double-buffered.
// ---------------------------------------------------------------------------
__global__ __launch_bounds__(256, 1) void gmm_main(const float* __restrict__ X,
                                                   const _Float16* __restrict__ wt,
                                                   const float* __restrict__ cst,
                                                   float* __restrict__ out)
{
    __shared__ float2 part[4][128];       // [slice][point] partial (mx, sm)

    const int tid  = threadIdx.x;
    const int wave = tid >> 6;            // = component slice
    const int lane = tid & 63;
    const int col  = lane & 31;
    const int h    = lane >> 5;
    const int ptbase = blockIdx.x * 128;

    // ---- build B fragments (x~) for 4 point-groups of 32 ----
    half8 bf[4][5];
    #pragma unroll
    for (int g = 0; g < 4; ++g) {
        const float* xr = X + (size_t)(ptbase + g * 32 + col) * DDIM;
        #pragma unroll
        for (int s = 0; s < 4; ++s) {
            int c = s * 2 + h;
            float4 lo = *(const float4*)(xr + c * 8);
            float4 hi = *(const float4*)(xr + c * 8 + 4);
            half8 v;
            v[0] = (_Float16)lo.x; v[1] = (_Float16)lo.y;
            v[2] = (_Float16)lo.z; v[3] = (_Float16)lo.w;
            v[4] = (_Float16)hi.x; v[5] = (_Float16)hi.y;
            v[6] = (_Float16)hi.z; v[7] = (_Float16)hi.w;
            bf[g][s] = v;
        }
        half8 v;
        #pragma unroll
        for (int e = 0; e < 8; ++e) v[e] = (_Float16)0.f;
        if (h == 0) { v[0] = (_Float16)1.f; v[1] = (_Float16)1.f; }
        bf[g][4] = v;   // augmented slice: pairs with (-b_hi, -b_lo)
    }

    const half8* wp = (const half8*)wt;
    const int comp0 = wave * 8;

    float mx[4], sm[4];
    #pragma unroll
    for (int g = 0; g < 4; ++g) { mx[g] = -INFINITY; sm[g] = 0.f; }

    half8 wfA[5], wfB[5];
    // preload tile-0 frags of first comp
    #pragma unroll
    for (int s = 0; s < 5; ++s)
        wfA[s] = wp[((size_t)comp0 * 2 + 0) * 5 * WFRAG_HALF8S + s * WFRAG_HALF8S + lane];

    #pragma unroll 1
    for (int q = 0; q < 8; ++q) {
        const int c = comp0 + q;

        // issue tile-1 frag loads (overlap with tile-0 MFMA below)
        #pragma unroll
        for (int s = 0; s < 5; ++s)
            wfB[s] = wp[((size_t)c * 2 + 1) * 5 * WFRAG_HALF8S + s * WFRAG_HALF8S + lane];

        float sP[4];

        {   // tile 0: z-rows 0..31
            floatx16 a0 = {0.f}, a1 = {0.f}, a2 = {0.f}, a3 = {0.f};
            #pragma unroll
            for (int s = 0; s < 5; ++s) {
                a0 = __builtin_amdgcn_mfma_f32_32x32x16_f16(wfA[s], bf[0][s], a0, 0, 0, 0);
                a1 = __builtin_amdgcn_mfma_f32_32x32x16_f16(wfA[s], bf[1][s], a1, 0, 0, 0);
                a2 = __builtin_amdgcn_mfma_f32_32x32x16_f16(wfA[s], bf[2][s], a2, 0, 0, 0);
                a3 = __builtin_amdgcn_mfma_f32_32x32x16_f16(wfA[s], bf[3][s], a3, 0, 0, 0);
            }
            float p0 = 0.f, p1 = 0.f, p2 = 0.f, p3 = 0.f;
            #pragma unroll
            for (int r = 0; r < 16; ++r) {
                p0 += a0[r] * a0[r]; p1 += a1[r] * a1[r];
                p2 += a2[r] * a2[r]; p3 += a3[r] * a3[r];
            }
            sP[0] = p0; sP[1] = p1; sP[2] = p2; sP[3] = p3;
        }

        // issue next comp's tile-0 loads (overlap with tile-1 MFMA below)
        if (q < 7) {
            #pragma unroll
            for (int s = 0; s < 5; ++s)
                wfA[s] = wp[((size_t)(c + 1) * 2 + 0) * 5 * WFRAG_HALF8S + s * WFRAG_HALF8S + lane];
        }

        {   // tile 1: z-rows 32..63
            floatx16 a0 = {0.f}, a1 = {0.f}, a2 = {0.f}, a3 = {0.f};
            #pragma unroll
            for (int s = 0; s < 5; ++s) {
                a0 = __builtin_amdgcn_mfma_f32_32x32x16_f16(wfB[s], bf[0][s], a0, 0, 0, 0);
                a1 = __builtin_amdgcn_mfma_f32_32x32x16_f16(wfB[s], bf[1][s], a1, 0, 0, 0);
                a2 = __builtin_amdgcn_mfma_f32_32x32x16_f16(wfB[s], bf[2][s], a2, 0, 0, 0);
                a3 = __builtin_amdgcn_mfma_f32_32x32x16_f16(wfB[s], bf[3][s], a3, 0, 0, 0);
            }
            float p0 = 0.f, p1 = 0.f, p2 = 0.f, p3 = 0.f;
            #pragma unroll
            for (int r = 0; r < 16; ++r) {
                p0 += a0[r] * a0[r]; p1 += a1[r] * a1[r];
                p2 += a2[r] * a2[r]; p3 += a3[r] * a3[r];
            }
            sP[0] += p0; sP[1] += p1; sP[2] += p2; sP[3] += p3;
        }

        const float ck = cst[c];
        #pragma unroll
        for (int g = 0; g < 4; ++g) {
            float sfull = sP[g] + __shfl_xor(sP[g], 32);
            float lp = ck - 0.5f * sfull;
            float nm = fmaxf(mx[g], lp);
            sm[g] = sm[g] * __expf(mx[g] - nm) + __expf(lp - nm);
            mx[g] = nm;
        }
    }

    // ---- merge the 4 slices in-block ----
    if (h == 0) {
        #pragma unroll
        for (int g = 0; g < 4; ++g)
            part[wave][g * 32 + col] = make_float2(mx[g], sm[g]);
    }
    __syncthreads();

    if (tid < 128) {
        float2 p0 = part[0][tid], p1 = part[1][tid];
        float2 p2 = part[2][tid], p3 = part[3][tid];
        float m = fmaxf(fmaxf(p0.x, p1.x), fmaxf(p2.x, p3.x));
        float s = p0.y * __expf(p0.x - m) + p1.y * __expf(p1.x - m)
                + p2.y * __expf(p2.x - m) + p3.y * __expf(p3.x - m);
        out[ptbase + tid] = m + logf(s);
    }
}

// ---------------------------------------------------------------------------
extern "C" void kernel_launch(void* const* d_in, const int* in_sizes, int n_in,
                              void* d_out, int out_size, void* d_ws, size_t ws_size,
                              hipStream_t stream) {
    const float* X   = (const float*)d_in[0];
    const float* loc = (const float*)d_in[1];
    const float* cov = (const float*)d_in[2];
    const float* pi  = (const float*)d_in[3];
    float* out = (float*)d_out;

    char* ws = (char*)d_ws;
    _Float16* wt = (_Float16*)ws;                              // 320 KB
    float* cstp  = (float*)(ws + (size_t)KCOMP * WCOMP_BYTES); // 128 B

    const int n = in_sizes[0] / DDIM;   // 65536

    gmm_prep<<<KCOMP, 64, 0, stream>>>(loc, cov, pi, wt, cstp);
    gmm_main<<<n / 128, 256, 0, stream>>>(X, wt, cstp, out);
}